// Round 4
// baseline (2216.390 us; speedup 1.0000x reference)
//
#include <hip/hip_runtime.h>
#include <math.h>

#define V 30000
#define E 200
#define T 100
#define N 2048
#define NITER 100
#define NBS 120          // sinkhorn blocks (barrier participants)
#define NBB 392          // bow-streaming blocks
#define NBTOT 512        // total grid
#define JPB 250          // words per sinkhorn block (120*250 = 30000)
#define PROW 128         // partial row stride in floats (b-dimension padded 120->128)
#define EPS_OT 1e-16f
#define EPS_LOG 1e-12f

// ws float offsets
#define OFF_KTW   0            // ushort[T*V] bf16 = 1,500,000 floats
#define OFF_KDT   1500000      // float[N*T]
#define OFF_WW    1704800      // V
#define OFF_DD    1734800      // N
#define OFF_TT    1736848      // 128
#define OFF_PM    1736976      // 128  word-softmax per-block max
#define OFF_PS    1737104      // 128  word-softmax per-block sum
#define OFF_ACCDT 1737232      // NITER*T (DT slow path only)
#define OFF_PART  1747232      // 2*T*PROW = 25,600 TW partials [buf][t][b]
#define OFF_VTW   1772832      // V
#define OFF_UDT   1802832      // N
#define OFF_UTW   1804880      // 128
#define OFF_VDT   1805008      // 128
#define OFF_DBL   1805136      // 16 floats = 8 doubles: [0]=dsr_slow [1]=l_dt [2]=l_tw [3]=bow_sum
#define OFF_CNT   1805152      // 128 ints: per-block monotone iteration flags
#define OFF_FLAG  1805280      // int: theta nonzero
#define OFF_KDTNZ 1805281      // int: any K_DT nonzero

__device__ __forceinline__ unsigned short f2bf(float f) {
    unsigned int u = __float_as_uint(f);
    return (unsigned short)((u + 0x7fffu + ((u >> 16) & 1u)) >> 16);
}
__device__ __forceinline__ float bf2f(unsigned short h) {
    return __uint_as_float(((unsigned int)h) << 16);
}

__device__ __forceinline__ float brsum(float x, float* red8) {
    int tid = threadIdx.x;
    for (int o = 32; o; o >>= 1) x += __shfl_down(x, o, 64);
    __syncthreads();
    if ((tid & 63) == 0) red8[tid >> 6] = x;
    __syncthreads();
    return (red8[0] + red8[1]) + (red8[2] + red8[3]);
}
__device__ __forceinline__ float brmax(float x, float* red8) {
    int tid = threadIdx.x;
    for (int o = 32; o; o >>= 1) x = fmaxf(x, __shfl_down(x, o, 64));
    __syncthreads();
    if ((tid & 63) == 0) red8[tid >> 6] = x;
    __syncthreads();
    return fmaxf(fmaxf(red8[0], red8[1]), fmaxf(red8[2], red8[3]));
}

// ---------- zeroing + row norms + word-softmax partials ----------
__global__ void k_pre(const float* __restrict__ we, const float* __restrict__ de,
                      const float* __restrict__ te, const float* __restrict__ wwgt,
                      float* ws) {
    __shared__ float red[256];
    int tid = threadIdx.x, b = blockIdx.x;
    int gid = b * 256 + tid;
    if (gid < NITER * T) ws[OFF_ACCDT + gid] = 0.f;
    if (gid < 16) ws[OFF_DBL + gid] = 0.f;
    if (gid < 128) ((int*)ws)[OFF_CNT + gid] = 0;
    if (gid < 2) ((int*)ws)[OFF_FLAG + gid] = 0;
    {   // squared row norms
        int r = gid;
        const float* src = nullptr; float* dst = nullptr; int row = 0;
        if (r < V)              { src = we; dst = ws + OFF_WW; row = r; }
        else if (r < V + N)     { src = de; dst = ws + OFF_DD; row = r - V; }
        else if (r < V + N + T) { src = te; dst = ws + OFF_TT; row = r - V - N; }
        if (src) {
            const float4* p = (const float4*)(src + (size_t)row * E);
            float s = 0.f;
            #pragma unroll 10
            for (int i = 0; i < E / 4; i++) { float4 v = p[i]; s += v.x*v.x + v.y*v.y + v.z*v.z + v.w*v.w; }
            dst[row] = s;
        }
    }
    if (b < 118) {  // word-softmax partials, merged per-block in k_persist
        int j = gid;
        float w = (j < V) ? wwgt[j] : -INFINITY;
        red[tid] = w; __syncthreads();
        for (int s = 128; s > 0; s >>= 1) { if (tid < s) red[tid] = fmaxf(red[tid], red[tid + s]); __syncthreads(); }
        float m = red[0]; __syncthreads();
        float e = (j < V) ? expf(w - m) : 0.f;
        red[tid] = e; __syncthreads();
        for (int s = 128; s > 0; s >>= 1) { if (tid < s) red[tid] += red[tid + s]; __syncthreads(); }
        if (tid == 0) { ws[OFF_PM + b] = m; ws[OFF_PS + b] = red[0]; }
    }
}

// ---------- K_TW[t][j] = bf16(exp(-2*sqdist)) ----------
__global__ void k_ktw(const float* __restrict__ we, const float* __restrict__ te, float* ws) {
    __shared__ float wt[8][256];
    __shared__ float tp[8][25];
    __shared__ float tts[25];
    int tid = threadIdx.x;
    int j0 = blockIdx.x * 256;
    int t0 = blockIdx.y * 25;
    int j = j0 + tid;
    int jl = (j < V) ? j : V - 1;
    float acc[25];
    #pragma unroll
    for (int i = 0; i < 25; i++) acc[i] = 0.f;
    if (tid < 25) tts[tid] = ws[OFF_TT + t0 + tid];
    for (int kk = 0; kk < E; kk += 8) {
        #pragma unroll
        for (int k = 0; k < 8; k++) wt[k][tid] = we[(size_t)jl * E + kk + k];
        if (tid < 200) { int i = tid >> 3; int k = tid & 7; tp[k][i] = te[(size_t)(t0 + i) * E + kk + k]; }
        __syncthreads();
        #pragma unroll
        for (int k = 0; k < 8; k++) {
            float w = wt[k][tid];
            #pragma unroll
            for (int i = 0; i < 25; i++) acc[i] += tp[k][i] * w;
        }
        __syncthreads();
    }
    if (j < V) {
        float wwj = ws[OFF_WW + j];
        unsigned short* kg = (unsigned short*)(ws + OFF_KTW);
        #pragma unroll
        for (int i = 0; i < 25; i++) {
            float M = tts[i] + wwj - 2.f * acc[i];
            kg[(size_t)(t0 + i) * V + j] = f2bf(expf(-2.f * M));
        }
    }
}

// ---------- K_DT[n][t] = exp(-3*sqdist), fp32, + any-nonzero flag ----------
__global__ void k_kdt(const float* __restrict__ de, const float* __restrict__ te, float* ws) {
    int gid = blockIdx.x * 256 + threadIdx.x;
    if (gid >= N * T) return;
    int n = gid / T; int t = gid - n * T;
    const float4* dp  = (const float4*)(de + (size_t)n * E);
    const float4* tpp = (const float4*)(te + (size_t)t * E);
    float s = 0.f;
    #pragma unroll 10
    for (int i = 0; i < E / 4; i++) { float4 a = dp[i], b = tpp[i]; s += a.x*b.x + a.y*b.y + a.z*b.z + a.w*b.w; }
    float M = ws[OFF_DD + n] + ws[OFF_TT + t] - 2.f * s;
    float kv = expf(-3.f * M);
    ws[OFF_KDT + gid] = kv;
    unsigned long long m = __ballot(kv != 0.f);
    if (m && (threadIdx.x & 63) == 0) atomicOr(((int*)ws) + OFF_KDTNZ, 1);
}

// ---------- persistent: 120 sinkhorn blocks + 392 bow-streaming blocks ----------
__global__ void __launch_bounds__(256, 3)
k_persist(const float* __restrict__ bow, const float* __restrict__ wwgt,
          const float* __restrict__ twgt, float* ws) {
    __shared__ unsigned short Kl[T * JPB];   // 50,000 B, [t][j] bf16
    __shared__ __align__(16) float v_tw[JPB];
    __shared__ __align__(16) float u_tw[T];
    __shared__ float b_dt[T];
    __shared__ float v_dt[T];
    __shared__ float u_dt[18];
    __shared__ float red8[8];
    int tid = threadIdx.x, b = blockIdx.x;

    if (b >= NBS) {  // ---- bow role: total-sum of train_bow ----
        const float4* b4 = (const float4*)bow;
        float s = 0.f;
        size_t total4 = (size_t)N * V / 4;
        for (size_t i = (size_t)(b - NBS) * 256 + tid; i < total4; i += (size_t)NBB * 256) {
            float4 x = b4[i]; s += (x.x + x.y) + (x.z + x.w);
        }
        float bs = brsum(s, red8);
        if (tid == 0) atomicAdd((double*)(ws + OFF_DBL) + 3, (double)bs);
        return;
    }

    // ---- sinkhorn role ----
    int j0 = b * JPB;
    int jl = tid;                                  // word lane, valid < JPB
    int kdtnz = *(((volatile int*)ws) + OFF_KDTNZ);

    // b_dt = softmax(topic_weights), block-redundant
    float x = (tid < T) ? twgt[tid] : -INFINITY;
    float mt = brmax(x, red8);
    float e = (tid < T) ? expf(x - mt) : 0.f;
    float se = brsum(e, red8);
    if (tid < T) b_dt[tid] = e / se;

    // merge word-softmax partials -> per-thread b_tw (register)
    float pm = (tid < 118) ? ws[OFF_PM + tid] : -INFINITY;
    float mw = brmax(pm, red8);
    float psc = (tid < 118) ? ws[OFF_PS + tid] * expf(ws[OFF_PM + tid] - mw) : 0.f;
    float Sw = brsum(psc, red8);
    float b_tw = (jl < JPB) ? expf(wwgt[j0 + jl] - mw) / Sw : 0.f;

    // load K slice: LDS [t][j] + per-thread packed register column
    const unsigned short* kg = (const unsigned short*)(ws + OFF_KTW);
    unsigned int col[50];
    #pragma unroll 4
    for (int t = 0; t < T; t++) {
        unsigned short kv = (jl < JPB) ? kg[(size_t)t * V + j0 + jl] : 0;
        if (jl < JPB) Kl[t * JPB + jl] = kv;
        if (t & 1) col[t >> 1] |= ((unsigned int)kv) << 16; else col[t >> 1] = kv;
    }
    if (tid < T) u_tw[tid] = 1.f / T;
    if (tid < 18) u_dt[tid] = 1.f / N;
    int nd = 17 + (b < 8 ? 1 : 0);
    int d0 = b * 17 + (b < 8 ? b : 8);
    __syncthreads();

    int* flag = ((int*)ws) + OFF_CNT;
    float* acc_dt = ws + OFF_ACCDT;

    for (int k = 0; k < NITER; k++) {
        int buf = k & 1;
        float* pbuf = ws + OFF_PART + (size_t)buf * T * PROW;
        // v-pass (registers + u broadcast)
        float vj = 0.f;
        if (jl < JPB) {
            float s = 0.f;
            #pragma unroll
            for (int t2 = 0; t2 < 50; t2++) {
                unsigned int c = col[t2];
                float2 uu = *(const float2*)&u_tw[2 * t2];
                s += __uint_as_float(c << 16) * uu.x;
                s += __uint_as_float(c & 0xffff0000u) * uu.y;
            }
            vj = b_tw / (s + EPS_OT);
            v_tw[jl] = vj;
        }
        __syncthreads();
        // partial K.v over my columns -> disjoint slot [t][b], relaxed write-through store
        if (tid < T) {
            const unsigned int* Kr = (const unsigned int*)&Kl[tid * JPB];
            float s = 0.f;
            #pragma unroll 5
            for (int jj = 0; jj < JPB / 2; jj++) {
                unsigned int c = Kr[jj];
                float2 vv = *(const float2*)&v_tw[2 * jj];
                s += __uint_as_float(c << 16) * vv.x;
                s += __uint_as_float(c & 0xffff0000u) * vv.y;
            }
            __hip_atomic_store(pbuf + tid * PROW + b, s,
                               __ATOMIC_RELAXED, __HIP_MEMORY_SCOPE_AGENT);
            if (kdtnz) {  // DT slow path (gated, correctness-only)
                float q = 0.f;
                for (int d = 0; d < nd; d++) q += ws[OFF_KDT + (size_t)(d0 + d) * T + tid] * u_dt[d];
                atomicAdd(&acc_dt[k * T + tid], q);
            }
        }
        __syncthreads();   // vmcnt(0) drain for all waves' stores before flag
        if (tid == 0)
            __hip_atomic_store(flag + b, k + 1, __ATOMIC_RELEASE, __HIP_MEMORY_SCOPE_AGENT);
        // poll: all 120 monotone flags >= k+1 (no RMW, 8 coalesced lines per poll)
        int target = k + 1;
        int ok;
        do {
            int f = 0x7fffffff;
            if (tid < NBS) f = __hip_atomic_load(flag + tid, __ATOMIC_RELAXED, __HIP_MEMORY_SCOPE_AGENT);
            ok = (f >= target);
        } while (!__syncthreads_and(ok));
        __builtin_amdgcn_fence(__ATOMIC_ACQUIRE, "agent");
        // readback partials -> u_tw (and DT slow path)
        if (tid < T) {
            const unsigned long long* pp = (const unsigned long long*)(pbuf + tid * PROW);
            float s = 0.f;
            #pragma unroll 10
            for (int q = 0; q < NBS / 2; q++) {
                unsigned long long w = __hip_atomic_load(pp + q, __ATOMIC_RELAXED, __HIP_MEMORY_SCOPE_AGENT);
                s += __uint_as_float((unsigned int)(w & 0xffffffffu));
                s += __uint_as_float((unsigned int)(w >> 32));
            }
            u_tw[tid] = (1.f / T) / (s + EPS_OT);
            if (kdtnz) {
                float ad = __hip_atomic_load(&acc_dt[k * T + tid], __ATOMIC_RELAXED, __HIP_MEMORY_SCOPE_AGENT);
                v_dt[tid] = b_dt[tid] / (ad + EPS_OT);
            }
        }
        __syncthreads();
        if (kdtnz) {
            if (tid < nd) {
                float s = 0.f;
                for (int t2 = 0; t2 < T; t2++) s += ws[OFF_KDT + (size_t)(d0 + tid) * T + t2] * v_dt[t2];
                u_dt[tid] = (1.f / N) / (s + EPS_OT);
            }
            __syncthreads();
        }
    }

    // loss_TW = sum u*K*v*M, M = -ln(K)/2 (skip K==0: transp elem exactly 0)
    float lt = 0.f;
    if (jl < JPB) {
        float vjf = v_tw[jl];
        #pragma unroll 5
        for (int t2 = 0; t2 < 50; t2++) {
            unsigned int c = col[t2];
            float k0 = __uint_as_float(c << 16);
            float k1 = __uint_as_float(c & 0xffff0000u);
            float2 uu = *(const float2*)&u_tw[2 * t2];
            if (k0 > 0.f) lt += uu.x * k0 * vjf * (-0.5f * logf(k0));
            if (k1 > 0.f) lt += uu.y * k1 * vjf * (-0.5f * logf(k1));
        }
    }
    float ltb = brsum(lt, red8);
    if (tid == 0) atomicAdd((double*)(ws + OFF_DBL) + 2, (double)ltb);

    if (kdtnz) {  // DT loss + publishes for k_dsr slow path
        if (jl < JPB) ws[OFF_VTW + j0 + jl] = v_tw[jl];
        if (b == 0 && tid < T) { ws[OFF_UTW + tid] = u_tw[tid]; ws[OFF_VDT + tid] = v_dt[tid]; }
        if (tid < nd) ws[OFF_UDT + d0 + tid] = u_dt[tid];
        float ld = 0.f; int nzloc = 0;
        if (tid < T) {
            for (int d = 0; d < nd; d++) {
                float kv = ws[OFF_KDT + (size_t)(d0 + d) * T + tid];
                if (kv > 0.f) ld += u_dt[d] * kv * v_dt[tid] * (-(1.f / 3.f) * logf(kv));
                if ((float)N * u_dt[d] * kv * v_dt[tid] != 0.f) nzloc = 1;
            }
        }
        float ldb = brsum(ld, red8);
        if (tid == 0) atomicAdd((double*)(ws + OFF_DBL) + 1, (double)ldb);
        if (nzloc) atomicOr(((int*)ws) + OFF_FLAG, 1);
    }
}

// ---------- DSR slow path only (theta != 0 somewhere) ----------
__global__ void k_dsr(const float* __restrict__ bow, float* ws) {
    if (*(volatile int*)(((int*)ws) + OFF_FLAG) == 0) return;
    __shared__ float th[32 * T];
    __shared__ float u2[T];
    __shared__ float vd[T];
    __shared__ float red[256];
    __shared__ int flag;
    int tid = threadIdx.x;
    int j0 = blockIdx.x * 256;
    int d0 = blockIdx.y * 32;
    if (tid < T) { vd[tid] = ws[OFF_VDT + tid]; u2[tid] = ws[OFF_UTW + tid]; }
    if (tid == 0) flag = 0;
    __syncthreads();
    bool nz = false;
    for (int idx = tid; idx < 32 * T; idx += 256) {
        int dl = idx / T; int t = idx - dl * T;
        float thv = (float)N * ws[OFF_UDT + d0 + dl] * ws[OFF_KDT + (size_t)(d0 + dl) * T + t] * vd[t];
        th[idx] = thv;
        nz |= (thv != 0.f);
    }
    if (nz) flag = 1;
    __syncthreads();
    int j = j0 + tid;
    float part = 0.f;
    const unsigned short* kg = (const unsigned short*)(ws + OFF_KTW);
    if (flag) {
        float acc[32];
        #pragma unroll
        for (int d = 0; d < 32; d++) acc[d] = 0.f;
        if (j < V) {
            float vj = ws[OFF_VTW + j];
            for (int t = 0; t < T; t++) {
                float kv = bf2f(kg[(size_t)t * V + j]);
                float beta = (float)T * u2[t] * kv * vj;
                #pragma unroll
                for (int d = 0; d < 32; d++) acc[d] += th[d * T + t] * beta;
            }
            for (int d = 0; d < 32; d++)
                part += bow[(size_t)(d0 + d) * V + j] * logf(acc[d] + EPS_LOG);
        }
    } else {
        if (j < V) {
            float sb = 0.f;
            #pragma unroll 8
            for (int d = 0; d < 32; d++) sb += bow[(size_t)(d0 + d) * V + j];
            part = sb * logf(EPS_LOG);
        }
    }
    red[tid] = part; __syncthreads();
    for (int s = 128; s > 0; s >>= 1) { if (tid < s) red[tid] += red[tid + s]; __syncthreads(); }
    if (tid == 0) atomicAdd((double*)(ws + OFF_DBL) + 0, (double)red[0]);
}

// ---------- combine ----------
__global__ void k_finish(float* ws, float* out) {
    if (threadIdx.x == 0 && blockIdx.x == 0) {
        double* dbl = (double*)(ws + OFF_DBL);
        int flag = *(((int*)ws) + OFF_FLAG);
        double dsr_sum = flag ? dbl[0] : dbl[3] * (double)logf(EPS_LOG);
        double ldsr = -dsr_sum / (double)N;
        double letp = dbl[1] + dbl[2];
        out[0] = (float)(ldsr + letp);
        out[1] = (float)ldsr;
        out[2] = (float)letp;
    }
}

extern "C" void kernel_launch(void* const* d_in, const int* in_sizes, int n_in,
                              void* d_out, int out_size, void* d_ws, size_t ws_size,
                              hipStream_t stream) {
    const float* bow  = (const float*)d_in[0];
    const float* de   = (const float*)d_in[1];
    const float* we   = (const float*)d_in[2];
    const float* te   = (const float*)d_in[3];
    const float* wwgt = (const float*)d_in[4];
    const float* twgt = (const float*)d_in[5];
    float* out = (float*)d_out;
    float* ws  = (float*)d_ws;

    k_pre<<<128, 256, 0, stream>>>(we, de, te, wwgt, ws);
    k_ktw<<<dim3(118, 4), 256, 0, stream>>>(we, te, ws);
    k_kdt<<<800, 256, 0, stream>>>(de, te, ws);
    void* args[] = { (void*)&bow, (void*)&wwgt, (void*)&twgt, (void*)&ws };
    hipError_t ce = hipLaunchCooperativeKernel((void*)k_persist, dim3(NBTOT), dim3(256),
                                               args, 0, stream);
    if (ce != hipSuccess)   // fallback: low-ID blocks dispatch first; 512 blocks co-resident at 52KB LDS
        k_persist<<<NBTOT, 256, 0, stream>>>(bow, wwgt, twgt, ws);
    k_dsr<<<dim3(118, 64), 256, 0, stream>>>(bow, ws);
    k_finish<<<1, 64, 0, stream>>>(ws, out);
}

// Round 5
// 1313.458 us; speedup vs baseline: 1.6874x; 1.6874x over previous
//
#include <hip/hip_runtime.h>
#include <math.h>

#define V 30000
#define E 200
#define T 100
#define N 2048
#define NITER 100
#define KSTR 112          // padded K_TW row stride in ushorts (224 B, 16B-aligned)
#define EPS_OT 1e-16f
#define EPS_LOG 1e-12f

// ws float offsets
#define OFF_KTW    0            // ushort[V*KSTR] bf16 word-major = 1,680,000 floats
#define OFF_KDT    1680000      // float[N*T]
#define OFF_WW     1884800      // V
#define OFF_DD     1914800      // N
#define OFF_TT     1916848      // 128
#define OFF_PM     1916976      // 128  word-softmax per-block max
#define OFF_PS     1917104      // 128  word-softmax per-block sum
#define OFF_BTW    1917232      // V    softmax(word_weights)
#define OFF_BDT    1947232      // 128  softmax(topic_weights)
#define OFF_ACC    1947360      // NITER*T   TW  K.v accumulators
#define OFF_ACCDT  1957360      // NITER*T   DT  K^T.u accumulators (gated)
#define OFF_VTW    1967360      // V
#define OFF_UDT    1997360      // N
#define OFF_UTW    1999408      // 128
#define OFF_VDT    1999536      // 128
#define OFF_DBL    1999664      // 16 floats = 8 doubles: [0]=dsr_slow [1]=l_dt [2]=l_tw [3]=bow_sum
#define OFF_FLAG   1999680      // int index: theta nonzero
#define OFF_KDTNZ  1999681      // int index: any K_DT nonzero

#define LOBF(u) __uint_as_float((u) << 16)
#define HIBF(u) __uint_as_float((u) & 0xffff0000u)

__device__ __forceinline__ unsigned short f2bf(float f) {
    unsigned int u = __float_as_uint(f);
    return (unsigned short)((u + 0x7fffu + ((u >> 16) & 1u)) >> 16);
}
__device__ __forceinline__ float bf2f(unsigned short h) {
    return __uint_as_float(((unsigned int)h) << 16);
}

__device__ __forceinline__ float brsum(float x, float* red8) {
    int tid = threadIdx.x;
    for (int o = 32; o; o >>= 1) x += __shfl_down(x, o, 64);
    __syncthreads();
    if ((tid & 63) == 0) red8[tid >> 6] = x;
    __syncthreads();
    return (red8[0] + red8[1]) + (red8[2] + red8[3]);
}

__device__ __forceinline__ void load_krow(const unsigned short* kg, int j, unsigned* ku) {
    const uint4* kp = (const uint4*)(kg + (size_t)j * KSTR);
    #pragma unroll
    for (int i = 0; i < 12; i++) {
        uint4 q = kp[i];
        ku[4*i] = q.x; ku[4*i+1] = q.y; ku[4*i+2] = q.z; ku[4*i+3] = q.w;
    }
    uint2 q2 = *(const uint2*)(((const unsigned*)kp) + 48);
    ku[48] = q2.x; ku[49] = q2.y;
}

// ---------- zeroing + row norms + word-softmax partials + topic softmax ----------
__global__ void k_pre(const float* __restrict__ we, const float* __restrict__ de,
                      const float* __restrict__ te, const float* __restrict__ wwgt,
                      const float* __restrict__ twgt, float* ws) {
    __shared__ float red[256];
    int tid = threadIdx.x, b = blockIdx.x;
    int gid = b * 256 + tid;
    if (gid < 2 * NITER * T) ws[OFF_ACC + gid] = 0.f;      // ACC + ACCDT contiguous
    if (gid < 16) ws[OFF_DBL + gid] = 0.f;
    if (gid < 2) ((int*)ws)[OFF_FLAG + gid] = 0;
    {   // squared row norms
        int r = gid;
        const float* src = nullptr; float* dst = nullptr; int row = 0;
        if (r < V)              { src = we; dst = ws + OFF_WW; row = r; }
        else if (r < V + N)     { src = de; dst = ws + OFF_DD; row = r - V; }
        else if (r < V + N + T) { src = te; dst = ws + OFF_TT; row = r - V - N; }
        if (src) {
            const float4* p = (const float4*)(src + (size_t)row * E);
            float s = 0.f;
            #pragma unroll 10
            for (int i = 0; i < E / 4; i++) { float4 v = p[i]; s += v.x*v.x + v.y*v.y + v.z*v.z + v.w*v.w; }
            dst[row] = s;
        }
    }
    if (b < 118) {  // word-softmax partials
        int j = gid;
        float w = (j < V) ? wwgt[j] : -INFINITY;
        red[tid] = w; __syncthreads();
        for (int s = 128; s > 0; s >>= 1) { if (tid < s) red[tid] = fmaxf(red[tid], red[tid + s]); __syncthreads(); }
        float m = red[0]; __syncthreads();
        float e = (j < V) ? expf(w - m) : 0.f;
        red[tid] = e; __syncthreads();
        for (int s = 128; s > 0; s >>= 1) { if (tid < s) red[tid] += red[tid + s]; __syncthreads(); }
        if (tid == 0) { ws[OFF_PM + b] = m; ws[OFF_PS + b] = red[0]; }
    } else if (b == 120) {  // topic softmax -> b_dt
        float w = (tid < T) ? twgt[tid] : -INFINITY;
        red[tid] = w; __syncthreads();
        for (int s = 128; s > 0; s >>= 1) { if (tid < s) red[tid] = fmaxf(red[tid], red[tid + s]); __syncthreads(); }
        float m = red[0]; __syncthreads();
        float e = (tid < T) ? expf(w - m) : 0.f;
        red[tid] = e; __syncthreads();
        for (int s = 128; s > 0; s >>= 1) { if (tid < s) red[tid] += red[tid + s]; __syncthreads(); }
        if (tid < T) ws[OFF_BDT + tid] = e / red[0];
    }
}

// ---------- merge word-softmax partials -> b_tw ----------
__global__ void k_pre2(const float* __restrict__ wwgt, float* ws) {
    __shared__ float red[128];
    int tid = threadIdx.x, b = blockIdx.x;
    float m = (tid < 118) ? ws[OFF_PM + tid] : -INFINITY;
    if (tid < 128) red[tid] = m;
    __syncthreads();
    for (int s = 64; s > 0; s >>= 1) { if (tid < s) red[tid] = fmaxf(red[tid], red[tid + s]); __syncthreads(); }
    float mw = red[0]; __syncthreads();
    float p = (tid < 118) ? ws[OFF_PS + tid] * expf(ws[OFF_PM + tid] - mw) : 0.f;
    if (tid < 128) red[tid] = p;
    __syncthreads();
    for (int s = 64; s > 0; s >>= 1) { if (tid < s) red[tid] += red[tid + s]; __syncthreads(); }
    float Sw = red[0];
    int j = b * 256 + tid;
    if (j < V) ws[OFF_BTW + j] = expf(wwgt[j] - mw) / Sw;
}

// ---------- K_TW[j][t] = bf16(exp(-2*sqdist)), word-major stride KSTR ----------
__global__ void k_ktw(const float* __restrict__ we, const float* __restrict__ te, float* ws) {
    __shared__ float wt[8][256];
    __shared__ float tp[8][25];
    __shared__ float tts[25];
    int tid = threadIdx.x;
    int j0 = blockIdx.x * 256;
    int t0 = blockIdx.y * 25;
    int j = j0 + tid;
    int jl = (j < V) ? j : V - 1;
    float acc[25];
    #pragma unroll
    for (int i = 0; i < 25; i++) acc[i] = 0.f;
    if (tid < 25) tts[tid] = ws[OFF_TT + t0 + tid];
    for (int kk = 0; kk < E; kk += 8) {
        #pragma unroll
        for (int k = 0; k < 8; k++) wt[k][tid] = we[(size_t)jl * E + kk + k];
        if (tid < 200) { int i = tid >> 3; int k = tid & 7; tp[k][i] = te[(size_t)(t0 + i) * E + kk + k]; }
        __syncthreads();
        #pragma unroll
        for (int k = 0; k < 8; k++) {
            float w = wt[k][tid];
            #pragma unroll
            for (int i = 0; i < 25; i++) acc[i] += tp[k][i] * w;
        }
        __syncthreads();
    }
    if (j < V) {
        float wwj = ws[OFF_WW + j];
        unsigned short* kg = (unsigned short*)(ws + OFF_KTW);
        #pragma unroll
        for (int i = 0; i < 25; i++) {
            float M = tts[i] + wwj - 2.f * acc[i];
            kg[(size_t)j * KSTR + t0 + i] = f2bf(expf(-2.f * M));
        }
    }
}

// ---------- K_DT[n][t] = exp(-3*sqdist), fp32, + any-nonzero flag ----------
__global__ void k_kdt(const float* __restrict__ de, const float* __restrict__ te, float* ws) {
    int gid = blockIdx.x * 256 + threadIdx.x;
    if (gid >= N * T) return;
    int n = gid / T; int t = gid - n * T;
    const float4* dp  = (const float4*)(de + (size_t)n * E);
    const float4* tpp = (const float4*)(te + (size_t)t * E);
    float s = 0.f;
    #pragma unroll 10
    for (int i = 0; i < E / 4; i++) { float4 a = dp[i], b = tpp[i]; s += a.x*b.x + a.y*b.y + a.z*b.z + a.w*b.w; }
    float M = ws[OFF_DD + n] + ws[OFF_TT + t] - 2.f * s;
    float kv = expf(-3.f * M);
    ws[OFF_KDT + gid] = kv;
    unsigned long long m = __ballot(kv != 0.f);
    if (m && (threadIdx.x & 63) == 0) atomicOr(((int*)ws) + OFF_KDTNZ, 1);
}

// ---------- one sinkhorn iteration ----------
// blocks 0..117  : TW (word-parallel, LDS block-reduce, 100 atomics)
// blocks 118..245: bow slice sum (k < 96)
// blocks 246..253: DT (gated on kdtnz)
__global__ void k_it(const float* __restrict__ bow, float* ws, int k) {
    __shared__ float sm[256 * 26];
    __shared__ float pr[256];
    __shared__ float u_sh[100];
    __shared__ float red8[8];
    int tid = threadIdx.x, b = blockIdx.x;

    if (b >= 118 && b < 246) {            // ---- bow role ----
        if (k >= 96) return;
        const float4* b4 = (const float4*)bow;
        size_t base = (size_t)k * 160000;
        float s = 0.f;
        for (int i = (b - 118) * 256 + tid; i < 160000; i += 128 * 256) {
            float4 x = b4[base + i]; s += (x.x + x.y) + (x.z + x.w);
        }
        float bs = brsum(s, red8);
        if (tid == 0) atomicAdd((double*)(ws + OFF_DBL) + 3, (double)bs);
        return;
    }

    if (b >= 246) {                       // ---- DT role (gated) ----
        if (((volatile int*)ws)[OFF_KDTNZ] == 0) return;
        int d = (b - 246) * 256 + tid;    // 0..2047
        if (tid < T) u_sh[tid] = (k == 0) ? 0.f
            : ws[OFF_BDT + tid] / (ws[OFF_ACCDT + (k - 1) * T + tid] + EPS_OT);
        __syncthreads();
        const float* Kr = ws + OFF_KDT + (size_t)d * T;
        float u;
        if (k == 0) u = 1.f / N;
        else {
            float s = 0.f;
            #pragma unroll 4
            for (int t = 0; t < T; t++) s += Kr[t] * u_sh[t];
            u = (1.f / N) / (s + EPS_OT);
        }
        #pragma unroll
        for (int c = 0; c < 4; c++) {
            #pragma unroll
            for (int i = 0; i < 25; i++) sm[tid * 26 + i] = Kr[25 * c + i] * u;
            __syncthreads();
            int g = tid >> 5, tl = tid & 31;
            float s2 = 0.f;
            if (tl < 25) {
                #pragma unroll 8
                for (int q = 0; q < 32; q++) s2 += sm[(g * 32 + q) * 26 + tl];
            }
            pr[g * 32 + tl] = s2;
            __syncthreads();
            if (tid < 25) {
                float r = 0.f;
                #pragma unroll
                for (int g2 = 0; g2 < 8; g2++) r += pr[g2 * 32 + tid];
                atomicAdd(&ws[OFF_ACCDT + k * T + 25 * c + tid], r);
            }
            __syncthreads();
        }
        return;
    }

    // ---- TW role ----
    const unsigned short* kg = (const unsigned short*)(ws + OFF_KTW);
    int j = b * 256 + tid;
    bool oob = (j >= V);
    int jc = oob ? V - 1 : j;
    unsigned ku[50];
    load_krow(kg, jc, ku);
    if (oob) {
        #pragma unroll
        for (int q = 0; q < 50; q++) ku[q] = 0;
    }
    if (tid < T) u_sh[tid] = (k == 0) ? 0.01f
        : 0.01f / (ws[OFF_ACC + (k - 1) * T + tid] + EPS_OT);
    __syncthreads();
    float s = 0.f;
    #pragma unroll
    for (int q = 0; q < 50; q++)
        s += LOBF(ku[q]) * u_sh[2 * q] + HIBF(ku[q]) * u_sh[2 * q + 1];
    float v = oob ? 0.f : ws[OFF_BTW + j] / (s + EPS_OT);
    if (k == NITER - 1 && !oob) ws[OFF_VTW + j] = v;
    #pragma unroll
    for (int c = 0; c < 4; c++) {
        #pragma unroll
        for (int i = 0; i < 25; i++) {
            int t = 25 * c + i;
            unsigned w = ku[t >> 1];
            float kt = (t & 1) ? HIBF(w) : LOBF(w);
            sm[tid * 26 + i] = kt * v;
        }
        __syncthreads();
        int g = tid >> 5, tl = tid & 31;
        float s2 = 0.f;
        if (tl < 25) {
            #pragma unroll 8
            for (int q = 0; q < 32; q++) s2 += sm[(g * 32 + q) * 26 + tl];
        }
        pr[g * 32 + tl] = s2;
        __syncthreads();
        if (tid < 25) {
            float r = 0.f;
            #pragma unroll
            for (int g2 = 0; g2 < 8; g2++) r += pr[g2 * 32 + tid];
            atomicAdd(&ws[OFF_ACC + k * T + 25 * c + tid], r);
        }
        __syncthreads();
    }
}

// ---------- post: final u, losses ----------
__global__ void k_post(float* ws) {
    __shared__ float u_sh[100];
    __shared__ float red8[8];
    int tid = threadIdx.x, b = blockIdx.x;
    if (b < 118) {   // TW loss
        if (tid < T) {
            float uf = 0.01f / (ws[OFF_ACC + (NITER - 1) * T + tid] + EPS_OT);
            u_sh[tid] = uf;
            if (b == 0) ws[OFF_UTW + tid] = uf;
        }
        __syncthreads();
        int j = b * 256 + tid;
        float lt = 0.f;
        if (j < V) {
            const unsigned short* kg = (const unsigned short*)(ws + OFF_KTW);
            unsigned ku[50];
            load_krow(kg, j, ku);
            float v = ws[OFF_VTW + j];
            #pragma unroll
            for (int q = 0; q < 50; q++) {
                float k0 = LOBF(ku[q]), k1 = HIBF(ku[q]);
                if (k0 > 0.f) lt += u_sh[2 * q]     * k0 * v * (-0.5f * logf(k0));
                if (k1 > 0.f) lt += u_sh[2 * q + 1] * k1 * v * (-0.5f * logf(k1));
            }
        }
        float ltb = brsum(lt, red8);
        if (tid == 0) atomicAdd((double*)(ws + OFF_DBL) + 2, (double)ltb);
    } else {        // DT (gated)
        if (((volatile int*)ws)[OFF_KDTNZ] == 0) return;
        if (tid < T) {
            float vf = ws[OFF_BDT + tid] / (ws[OFF_ACCDT + (NITER - 1) * T + tid] + EPS_OT);
            u_sh[tid] = vf;
            if (b == 118) ws[OFF_VDT + tid] = vf;
        }
        __syncthreads();
        int d = (b - 118) * 256 + tid;
        const float* Kr = ws + OFF_KDT + (size_t)d * T;
        float s = 0.f;
        #pragma unroll 4
        for (int t = 0; t < T; t++) s += Kr[t] * u_sh[t];
        float u = (1.f / N) / (s + EPS_OT);
        ws[OFF_UDT + d] = u;
        float ld = 0.f; int nz = 0;
        for (int t = 0; t < T; t++) {
            float kv = Kr[t];
            if (kv > 0.f) ld += u * kv * u_sh[t] * (-(1.f / 3.f) * logf(kv));
            if ((float)N * u * kv * u_sh[t] != 0.f) nz = 1;
        }
        float ldb = brsum(ld, red8);
        if (tid == 0) atomicAdd((double*)(ws + OFF_DBL) + 1, (double)ldb);
        if (nz) atomicOr(((int*)ws) + OFF_FLAG, 1);
    }
}

// ---------- DSR slow path only (theta != 0 somewhere) ----------
__global__ void k_dsr(const float* __restrict__ bow, float* ws) {
    if (*(volatile int*)(((int*)ws) + OFF_FLAG) == 0) return;
    __shared__ float th[32 * T];
    __shared__ float u2[T];
    __shared__ float vd[T];
    __shared__ float red[256];
    __shared__ int flag;
    int tid = threadIdx.x;
    int j0 = blockIdx.x * 256;
    int d0 = blockIdx.y * 32;
    if (tid < T) { vd[tid] = ws[OFF_VDT + tid]; u2[tid] = ws[OFF_UTW + tid]; }
    if (tid == 0) flag = 0;
    __syncthreads();
    bool nz = false;
    for (int idx = tid; idx < 32 * T; idx += 256) {
        int dl = idx / T; int t = idx - dl * T;
        float thv = (float)N * ws[OFF_UDT + d0 + dl] * ws[OFF_KDT + (size_t)(d0 + dl) * T + t] * vd[t];
        th[idx] = thv;
        nz |= (thv != 0.f);
    }
    if (nz) flag = 1;
    __syncthreads();
    int j = j0 + tid;
    float part = 0.f;
    const unsigned short* kg = (const unsigned short*)(ws + OFF_KTW);
    if (flag) {
        float acc[32];
        #pragma unroll
        for (int d = 0; d < 32; d++) acc[d] = 0.f;
        if (j < V) {
            float vj = ws[OFF_VTW + j];
            for (int t = 0; t < T; t++) {
                float kv = bf2f(kg[(size_t)j * KSTR + t]);
                float beta = (float)T * u2[t] * kv * vj;
                #pragma unroll
                for (int d = 0; d < 32; d++) acc[d] += th[d * T + t] * beta;
            }
            for (int d = 0; d < 32; d++)
                part += bow[(size_t)(d0 + d) * V + j] * logf(acc[d] + EPS_LOG);
        }
    } else {
        if (j < V) {
            float sb = 0.f;
            #pragma unroll 8
            for (int d = 0; d < 32; d++) sb += bow[(size_t)(d0 + d) * V + j];
            part = sb * logf(EPS_LOG);
        }
    }
    red[tid] = part; __syncthreads();
    for (int s = 128; s > 0; s >>= 1) { if (tid < s) red[tid] += red[tid + s]; __syncthreads(); }
    if (tid == 0) atomicAdd((double*)(ws + OFF_DBL) + 0, (double)red[0]);
}

// ---------- combine ----------
__global__ void k_finish(float* ws, float* out) {
    if (threadIdx.x == 0 && blockIdx.x == 0) {
        double* dbl = (double*)(ws + OFF_DBL);
        int flag = ((int*)ws)[OFF_FLAG];
        double dsr_sum = flag ? dbl[0] : dbl[3] * (double)logf(EPS_LOG);
        double ldsr = -dsr_sum / (double)N;
        double letp = dbl[1] + dbl[2];
        out[0] = (float)(ldsr + letp);
        out[1] = (float)ldsr;
        out[2] = (float)letp;
    }
}

extern "C" void kernel_launch(void* const* d_in, const int* in_sizes, int n_in,
                              void* d_out, int out_size, void* d_ws, size_t ws_size,
                              hipStream_t stream) {
    const float* bow  = (const float*)d_in[0];
    const float* de   = (const float*)d_in[1];
    const float* we   = (const float*)d_in[2];
    const float* te   = (const float*)d_in[3];
    const float* wwgt = (const float*)d_in[4];
    const float* twgt = (const float*)d_in[5];
    float* out = (float*)d_out;
    float* ws  = (float*)d_ws;

    k_pre<<<128, 256, 0, stream>>>(we, de, te, wwgt, twgt, ws);
    k_pre2<<<118, 256, 0, stream>>>(wwgt, ws);
    k_ktw<<<dim3(118, 4), 256, 0, stream>>>(we, te, ws);
    k_kdt<<<800, 256, 0, stream>>>(de, te, ws);
    for (int k = 0; k < NITER; k++)
        k_it<<<254, 256, 0, stream>>>(bow, ws, k);
    k_post<<<126, 256, 0, stream>>>(ws);
    k_dsr<<<dim3(118, 64), 256, 0, stream>>>(bow, ws);
    k_finish<<<1, 64, 0, stream>>>(ws, out);
}